// Round 3
// baseline (48.203 us; speedup 1.0000x reference)
//
#include <hip/hip_runtime.h>
#include <math.h>

#define NPART 8192
#define R2c   0.0025f     /* RADIUS^2 */
#define CR2c  0.01f       /* (2*RADIUS)^2 */
#define ACCS  0.005f
#define MAXV  0.05f
#define EPSV  1e-06f
#define NSWP  2048        /* sweep blocks: 4 rows/block (2 pairs x jsplit2) */
#define OUT_SCALARS 57344 /* offset of the 6 scalar outputs in d_out */

#define WRED(v) do { \
    v += __shfl_xor(v, 32); v += __shfl_xor(v, 16); v += __shfl_xor(v, 8); \
    v += __shfl_xor(v, 4);  v += __shfl_xor(v, 2);  v += __shfl_xor(v, 1); \
  } while (0)

// ---------------------------------------------------------------- prep ----
// Per row: pos (float2), posc (px,py,cj,fj), yext (y0..y3, cj, pad[3]).
__global__ __launch_bounds__(256) void prep_kernel(
    const float* __restrict__ x, const float* __restrict__ wn,
    float2* __restrict__ pos, float4* __restrict__ posc,
    float* __restrict__ yext)
{
  int i = blockIdx.x * blockDim.x + threadIdx.x;
  if (i >= NPART) return;
  const float* xi = x + i * 7;
  float v0 = xi[0], v1 = xi[1], v2 = xi[2], v3 = xi[3];
  float v4 = xi[4], v5 = xi[5], v6 = xi[6];
  float ci = (v4 > 0.5f) ? 1.0f : 0.0f;
  pos[i] = make_float2(v0, v1);
  posc[i] = make_float4(v0, v1, ci, 1.0f - ci);
  float y[4];
#pragma unroll
  for (int c = 0; c < 4; ++c) {
    float s = v0 * wn[0 * 4 + c];
    s += v1 * wn[1 * 4 + c];
    s += v2 * wn[2 * 4 + c];
    s += v3 * wn[3 * 4 + c];
    s += v4 * wn[4 * 4 + c];
    s += v5 * wn[5 * 4 + c];
    s += v6 * wn[6 * 4 + c];
    y[c] = s;
  }
  float* ye = yext + i * 8;
  ye[0] = y[0]; ye[1] = y[1]; ye[2] = y[2]; ye[3] = y[3];
  ye[4] = ci; ye[5] = 0.f; ye[6] = 0.f; ye[7] = 0.f;
}

// ---------------------------------------------------------------- scan ----
// Deterministic partition of rows by type (no atomics): 1024-thread block,
// 8 rows/thread, Hillis-Steele prefix over per-thread cell counts, then
// ordered compaction into cell_list / food_list (+16 sentinel -1 pads).
__global__ __launch_bounds__(1024) void scan_kernel(
    const float* __restrict__ x, int* __restrict__ cell_list,
    int* __restrict__ food_list, int* __restrict__ ncbuf)
{
  __shared__ int s[1024];
  const int t = threadIdx.x;
  int flags = 0, cnt = 0;
#pragma unroll
  for (int k = 0; k < 8; ++k) {
    int i = t * 8 + k;
    int c = (x[i * 7 + 4] > 0.5f) ? 1 : 0;
    flags |= c << k; cnt += c;
  }
  s[t] = cnt;
  __syncthreads();
  for (int off = 1; off < 1024; off <<= 1) {
    int v = s[t];
    int u = (t >= off) ? s[t - off] : 0;
    __syncthreads();
    s[t] = v + u;
    __syncthreads();
  }
  const int incl = s[t];
  const int total = s[1023];
  int cbase = incl - cnt;
  int fbase = t * 8 - cbase;
#pragma unroll
  for (int k = 0; k < 8; ++k) {
    int i = t * 8 + k;
    if ((flags >> k) & 1) cell_list[cbase++] = i;
    else                  food_list[fbase++] = i;
  }
  if (t == 0) ncbuf[0] = total;
  if (t == 1023) {
    int nf = NPART - total;
    for (int k = 0; k < 16; ++k) {
      cell_list[total + k] = -1;
      food_list[nf + k] = -1;
    }
  }
}

// --------------------------------------------------------------- sweep ----
// Block = 4 waves = 2 row-pairs x 2 j-halves; 2048 blocks = 8192 waves
// (one per row, fully resident at 8 waves/SIMD). Blocks < nbc take the
// cell path (R radius only; yext loaded under a ~22%-taken branch); the
// rest take the food path (CR+R counts, fully branchless, cj/fj packed
// in posc). Halves combine via LDS; lane0 of half-0 runs the epilogue.
#define PROCJ_CELL(PX_, PY_, J)                                               \
  do {                                                                        \
    float dx0 = __fsub_rn(p0x, (PX_)), dy0 = __fsub_rn(p0y, (PY_));           \
    float dx1 = __fsub_rn(p1x, (PX_)), dy1 = __fsub_rn(p1y, (PY_));           \
    float d20 = __fadd_rn(__fmul_rn(dx0, dx0), __fmul_rn(dy0, dy0));          \
    float d21 = __fadd_rn(__fmul_rn(dx1, dx1), __fmul_rn(dy1, dy1));          \
    bool r0 = d20 < R2c, r1 = d21 < R2c;                                      \
    if (r0 || r1) {                                                           \
      const float* ye = yext + (size_t)(J) * 8;                               \
      float y0 = ye[0], y1 = ye[1], y2 = ye[2], y3 = ye[3], cj = ye[4];       \
      cnt0 += r0 ? 1.f : 0.f; cnb0 += r0 ? cj : 0.f;                          \
      ns0x += r0 ? y0 : 0.f; ns0y += r0 ? y1 : 0.f;                           \
      ns0z += r0 ? y2 : 0.f; ns0w += r0 ? y3 : 0.f;                           \
      cnt1 += r1 ? 1.f : 0.f; cnb1 += r1 ? cj : 0.f;                          \
      ns1x += r1 ? y0 : 0.f; ns1y += r1 ? y1 : 0.f;                           \
      ns1z += r1 ? y2 : 0.f; ns1w += r1 ? y3 : 0.f;                           \
    }                                                                         \
  } while (0)

#define PROCJ_FOOD(V)                                                         \
  do {                                                                        \
    float dx0 = __fsub_rn(p0x, (V).x), dy0 = __fsub_rn(p0y, (V).y);           \
    float dx1 = __fsub_rn(p1x, (V).x), dy1 = __fsub_rn(p1y, (V).y);           \
    float d20 = __fadd_rn(__fmul_rn(dx0, dx0), __fmul_rn(dy0, dy0));          \
    float d21 = __fadd_rn(__fmul_rn(dx1, dx1), __fmul_rn(dy1, dy1));          \
    cons0 += (d20 < CR2c) ? (V).z : 0.f;                                      \
    cons1 += (d21 < CR2c) ? (V).z : 0.f;                                      \
    fcnt0 += (d20 < R2c) ? (V).w : 0.f;                                       \
    fcnt1 += (d21 < R2c) ? (V).w : 0.f;                                       \
  } while (0)

__global__ __launch_bounds__(256, 8) void sweep_kernel(
    const float* __restrict__ x, const float* __restrict__ wself,
    const float* __restrict__ bvec, const float2* __restrict__ pos,
    const float4* __restrict__ posc, const float* __restrict__ yext,
    const int* __restrict__ cell_list, const int* __restrict__ food_list,
    const int* __restrict__ ncbuf, float* __restrict__ out,
    float* __restrict__ partials)
{
  __shared__ float s_acc[4][12];
  __shared__ float s_scal[2][6];
  const int lane = threadIdx.x & 63;
  const int wave = threadIdx.x >> 6;
  const int pairp = wave >> 1; /* which row-pair in block  */
  const int half = wave & 1;   /* which j half-range       */
  const int b = blockIdx.x;
  const int nc = ncbuf[0];
  const int nbc = (nc + 3) >> 2;
  const int nf = NPART - nc;
  const bool isCell = (b < nbc);

  if (!isCell && (b - nbc) * 4 >= nf) { /* uniform: fully-padded food block */
    if (threadIdx.x == 0) {
#pragma unroll
      for (int k = 0; k < 6; ++k) partials[b * 6 + k] = 0.f;
    }
    return;
  }

  int i0, i1;
  {
    int s0 = (isCell ? b * 4 : (b - nbc) * 4) + pairp * 2;
    const int* lst = isCell ? cell_list : food_list;
    i0 = lst[s0]; i1 = lst[s0 + 1];
  }
  const int gi0 = (i0 >= 0) ? i0 : 0;
  const int gi1 = (i1 >= 0) ? i1 : 0;
  float2 pi0 = pos[gi0];
  float2 pi1 = pos[gi1];
  const float p0x = (i0 >= 0) ? pi0.x : 1e9f;
  const float p0y = (i0 >= 0) ? pi0.y : 1e9f;
  const float p1x = (i1 >= 0) ? pi1.x : 1e9f;
  const float p1y = (i1 >= 0) ? pi1.y : 1e9f;

  if (isCell) {
    float ns0x = 0.f, ns0y = 0.f, ns0z = 0.f, ns0w = 0.f;
    float ns1x = 0.f, ns1y = 0.f, ns1z = 0.f, ns1w = 0.f;
    float cnt0 = 0.f, cnt1 = 0.f, cnb0 = 0.f, cnb1 = 0.f;
    const float4* __restrict__ posq = (const float4*)pos;
    const int off = half * 2048;
    float4 A = posq[off + lane];
    float4 B = posq[off + 64 + lane];
    for (int it = 0; it < 16; ++it) {
      const int nidx = off + ((it + 1) & 15) * 128 + lane;
      float4 nA = posq[nidx];
      float4 nB = posq[nidx + 64];
      const int j0 = half * 4096 + it * 256 + 2 * lane;
      PROCJ_CELL(A.x, A.y, j0);
      PROCJ_CELL(A.z, A.w, j0 + 1);
      PROCJ_CELL(B.x, B.y, j0 + 128);
      PROCJ_CELL(B.z, B.w, j0 + 129);
      A = nA; B = nB;
    }
    WRED(ns0x); WRED(ns0y); WRED(ns0z); WRED(ns0w);
    WRED(ns1x); WRED(ns1y); WRED(ns1z); WRED(ns1w);
    WRED(cnt0); WRED(cnt1); WRED(cnb0); WRED(cnb1);
    if (lane == 0) {
      float* sa = s_acc[wave];
      sa[0] = ns0x; sa[1] = ns0y; sa[2] = ns0z; sa[3] = ns0w;
      sa[4] = cnt0; sa[5] = cnb0;
      sa[6] = ns1x; sa[7] = ns1y; sa[8] = ns1z; sa[9] = ns1w;
      sa[10] = cnt1; sa[11] = cnb1;
    }
  } else {
    float cons0 = 0.f, cons1 = 0.f, fcnt0 = 0.f, fcnt1 = 0.f;
    const int off = half * 4096;
    float4 A = posc[off + lane];
    float4 B = posc[off + 64 + lane];
    for (int it = 0; it < 32; ++it) {
      const int nidx = off + ((it + 1) & 31) * 128 + lane;
      float4 nA = posc[nidx];
      float4 nB = posc[nidx + 64];
      PROCJ_FOOD(A);
      PROCJ_FOOD(B);
      A = nA; B = nB;
    }
    WRED(cons0); WRED(cons1); WRED(fcnt0); WRED(fcnt1);
    if (lane == 0) {
      float* sa = s_acc[wave];
      sa[0] = cons0; sa[1] = fcnt0; sa[6] = cons1; sa[7] = fcnt1;
      sa[2] = 0.f; sa[3] = 0.f; sa[4] = 0.f; sa[5] = 0.f;
      sa[8] = 0.f; sa[9] = 0.f; sa[10] = 0.f; sa[11] = 0.f;
    }
  }
  __syncthreads();

  if (half == 0 && lane == 0) {
    const float* a = s_acc[wave];
    const float* c = s_acc[wave + 1];
    float velbx = 0.f, velby = 0.f, border = 0.f;
    float foodr = 0.f, deadc = 0.f, visf = 0.f;
#pragma unroll
    for (int r = 0; r < 2; ++r) {
      const int i = (r == 0) ? i0 : i1;
      if (i < 0) continue;
      const int o = r * 6;
      const float* xi = x + i * 7;
      float px = xi[0], py = xi[1], vx = xi[2], vy = xi[3];
      float typ = xi[4], x5 = xi[5], x6 = xi[6];
      if (isCell) {
        float nsx = (a[o + 0] + c[o + 0]);
        float nsy = (a[o + 1] + c[o + 1]);
        float nsz = (a[o + 2] + c[o + 2]);
        float nsw = (a[o + 3] + c[o + 3]);
        float cntv = a[o + 4] + c[o + 4];
        float cnbv = a[o + 5] + c[o + 5];
        const float* yi = yext + (size_t)i * 8;
        nsx -= yi[0]; nsy -= yi[1]; nsz -= yi[2]; nsw -= yi[3];
        float cnbn = cnbv - 1.0f;     /* remove self (cell) */
        float foodv = cntv - cnbv;    /* self cancels       */
        float h0 = bvec[0] + px * wself[0] + py * wself[4] + vx * wself[8] +
                   vy * wself[12] + typ * wself[16] + x5 * wself[20] +
                   x6 * wself[24] + nsx;
        float h1 = bvec[1] + px * wself[1] + py * wself[5] + vx * wself[9] +
                   vy * wself[13] + typ * wself[17] + x5 * wself[21] +
                   x6 * wself[25] + nsy;
        float h2 = bvec[2] + px * wself[2] + py * wself[6] + vx * wself[10] +
                   vy * wself[14] + typ * wself[18] + x5 * wself[22] +
                   x6 * wself[26] + nsz;
        float h3 = bvec[3] + px * wself[3] + py * wself[7] + vx * wself[11] +
                   vy * wself[15] + typ * wself[19] + x5 * wself[23] +
                   x6 * wself[27] + nsw;
        h0 *= ACCS; h1 *= ACCS; h2 *= ACCS; h3 *= ACCS;
        float nvx = fminf(fmaxf(vx + h0, -MAXV), MAXV);
        float nvy = fminf(fmaxf(vy + h1, -MAXV), MAXV);
        float npx = px + nvx, npy = py + nvy;
        float ax = fabsf(npx), ay = fabsf(npy);
        if (ax > 1.0f) border += logf(ax + EPSV);
        if (ay > 1.0f) border += logf(ay + EPSV);
        bool dead = (cnbn < 2.5f);
        float keep = dead ? 0.0f : 1.0f;
        float* orow = out + (size_t)i * 7;
        orow[0] = npx * keep; orow[1] = npy * keep;
        orow[2] = nvx * keep; orow[3] = nvy * keep;
        orow[4] = typ * keep; orow[5] = h2 * keep; orow[6] = h3 * keep;
        velbx += fabsf(nvx); velby += fabsf(nvy);
        if (dead) deadc += 1.0f;
        visf += foodv;
      } else {
        float consv = a[o + 0] + c[o + 0];
        float fcntv = a[o + 1] + c[o + 1];
        float nvx = fminf(fmaxf(vx, -MAXV), MAXV);
        float nvy = fminf(fmaxf(vy, -MAXV), MAXV);
        float npx = px + nvx, npy = py + nvy;
        float ax = fabsf(npx), ay = fabsf(npy);
        if (ax > 1.0f) border += logf(ax + EPSV);
        if (ay > 1.0f) border += logf(ay + EPSV);
        bool consumed = (consv > 4.5f);
        float keep = consumed ? 0.0f : 1.0f;
        float* orow = out + (size_t)i * 7;
        orow[0] = npx * keep; orow[1] = npy * keep;
        orow[2] = nvx * keep; orow[3] = nvy * keep;
        orow[4] = 0.f; orow[5] = 0.f; orow[6] = 0.f;
        velbx += fabsf(nvx); velby += fabsf(nvy);
        if (consumed) foodr += 1.0f;
        visf += fcntv - 1.0f; /* remove self (food) */
      }
    }
    s_scal[pairp][0] = velbx; s_scal[pairp][1] = velby;
    s_scal[pairp][2] = border; s_scal[pairp][3] = foodr;
    s_scal[pairp][4] = deadc; s_scal[pairp][5] = visf;
  }
  __syncthreads();
  if (threadIdx.x == 0) {
#pragma unroll
    for (int k = 0; k < 6; ++k)
      partials[b * 6 + k] = s_scal[0][k] + s_scal[1][k];
  }
}

// ------------------------------------------------------------- reduce -----
__global__ __launch_bounds__(384) void reduce_kernel(
    const float* __restrict__ partials, float* __restrict__ out)
{
  int wave = threadIdx.x >> 6, lane = threadIdx.x & 63;
  if (wave >= 6) return;
  float s = 0.f;
  for (int bidx = lane; bidx < NSWP; bidx += 64) s += partials[bidx * 6 + wave];
  WRED(s);
  if (lane == 0) {
    float v = s;
    if (wave < 2) v = s * (1.0f / 8192.0f); /* vel_bonus = mean */
    out[OUT_SCALARS + wave] = v;
  }
}

// ------------------------------------------------------------- launch -----
extern "C" void kernel_launch(void* const* d_in, const int* in_sizes, int n_in,
                              void* d_out, int out_size, void* d_ws, size_t ws_size,
                              hipStream_t stream)
{
  const float* x      = (const float*)d_in[0];
  const float* wself  = (const float*)d_in[1];
  const float* wneigh = (const float*)d_in[2];
  const float* bvec   = (const float*)d_in[3];
  float* out = (float*)d_out;
  float* ws  = (float*)d_ws;

  float2* pos   = (float2*)ws;                      /* 2N floats           */
  float4* posc  = (float4*)(ws + 2 * NPART);        /* 4N floats           */
  float*  yext  = ws + 6 * NPART;                   /* 8N floats (32B rec) */
  float*  partials = ws + 14 * NPART;               /* NSWP*6 floats       */
  int* cell_list = (int*)(ws + 14 * NPART + NSWP * 6); /* N+16 ints        */
  int* food_list = cell_list + NPART + 16;             /* N+16 ints        */
  int* ncbuf     = food_list + NPART + 16;             /* 1 int            */

  hipLaunchKernelGGL(prep_kernel, dim3(NPART / 256), dim3(256), 0, stream,
                     x, wneigh, pos, posc, yext);
  hipLaunchKernelGGL(scan_kernel, dim3(1), dim3(1024), 0, stream,
                     x, cell_list, food_list, ncbuf);
  hipLaunchKernelGGL(sweep_kernel, dim3(NSWP), dim3(256), 0, stream,
                     x, wself, bvec, pos, posc, yext, cell_list, food_list,
                     ncbuf, out, partials);
  hipLaunchKernelGGL(reduce_kernel, dim3(1), dim3(384), 0, stream,
                     partials, out);
}